// Round 7
// baseline (258.335 us; speedup 1.0000x reference)
//
#include <hip/hip_runtime.h>

#define PD 88      // sequences == W dim
#define TD 128     // time == T dim
#define I0 133     // layer0 input size
#define HID 24     // LSTM hidden
#define GD 96      // gates = 4*HID
#define CD 48      // channels = 2*HID
#define NH 4       // heads
#define HDIM 12    // head dim
#define KW 13      // neighborhood

__device__ __forceinline__ int imin(int a,int b){return a<b?a:b;}
__device__ __forceinline__ int imax(int a,int b){return a>b?a:b;}

__device__ __forceinline__ float actg(float sa, float ss, float sb, float x) {
  return sa * __builtin_amdgcn_rcpf(1.f + __expf(-ss * x)) + sb;
}
// f32 -> bf16 RTNE
__device__ __forceinline__ unsigned short f2bf(float f) {
  unsigned u = __float_as_uint(f);
  u = u + 0x7fffu + ((u >> 16) & 1u);
  return (unsigned short)(u >> 16);
}

// ============ xg layer0 (r5-proven: 384 thr = 96 cols x 4 row-groups) ============
__global__ __launch_bounds__(384) void xg0_kernel(
    const float* __restrict__ x,
    const float* __restrict__ wf, const float* __restrict__ wb,
    const float* __restrict__ bif, const float* __restrict__ bhf,
    const float* __restrict__ bib, const float* __restrict__ bhb,
    float* __restrict__ xg) {
  __shared__ __align__(16) float wl[GD*I0];   // 51.1 KB flat [96][133]
  __shared__ __align__(16) float al[32*136];  // 17.4 KB
  const int dir = blockIdx.y;
  const float* W = dir ? wb : wf;
  for (int idx = threadIdx.x; idx < GD*I0/4; idx += 384)
    reinterpret_cast<float4*>(wl)[idx] = reinterpret_cast<const float4*>(W)[idx];
  const int r0 = blockIdx.x * 32;
  const int p = r0 >> 7, t0 = r0 & 127;
  for (int idx = threadIdx.x; idx < 32*I0; idx += 384) {
    int r = idx / I0, i = idx - r*I0;
    al[r*136 + i] = x[((size_t)(t0+r)*PD + p)*I0 + i];
  }
  __syncthreads();
  const int c  = threadIdx.x % GD;
  const int rg = threadIdx.x / GD;
  const float bias = (dir ? (bib[c]+bhb[c]) : (bif[c]+bhf[c]));
  float acc[8];
#pragma unroll
  for (int r=0;r<8;r++) acc[r]=bias;
  const float* wrow = wl + c*I0;
  const float* ab = al + rg*8*136;
#pragma unroll 1
  for (int i0=0; i0<132; i0+=4) {
    float w0=wrow[i0], w1=wrow[i0+1], w2=wrow[i0+2], w3=wrow[i0+3];
#pragma unroll
    for (int r=0;r<8;r++) {
      float4 a4 = *reinterpret_cast<const float4*>(&ab[r*136 + i0]);  // broadcast
      acc[r] += a4.x*w0 + a4.y*w1 + a4.z*w2 + a4.w*w3;
    }
  }
  {
    float wlast = wrow[132];
#pragma unroll
    for (int r=0;r<8;r++) acc[r] += ab[r*136 + 132]*wlast;
  }
  float* op = xg + ((size_t)dir*PD*TD + r0 + rg*8)*GD + c;
#pragma unroll
  for (int r=0;r<8;r++) op[(size_t)r*GD] = acc[r];
}

// ============ xg layer1 (r4-proven) ============
__global__ __launch_bounds__(192) void xg1_kernel(
    const float* __restrict__ h0,
    const float* __restrict__ wf, const float* __restrict__ wb,
    const float* __restrict__ bif, const float* __restrict__ bhf,
    const float* __restrict__ bib, const float* __restrict__ bhb,
    float* __restrict__ xg) {
  __shared__ float wl[192*53];
  __shared__ __align__(16) float al[32*CD];
  for (int idx = threadIdx.x; idx < 192*CD; idx += 192) {
    int cc = idx / CD, i = idx - cc*CD;
    wl[cc*53 + i] = (cc < GD) ? wf[cc*CD + i] : wb[(cc-GD)*CD + i];
  }
  const int r0 = blockIdx.x * 32;
  for (int idx = threadIdx.x; idx < 32*CD/4; idx += 192)
    reinterpret_cast<float4*>(al)[idx] =
        reinterpret_cast<const float4*>(h0 + (size_t)r0*CD)[idx];
  __syncthreads();
  const int c = threadIdx.x;
  const int dir = c >= GD;
  const int g = c - dir*GD;
  const float bias = dir ? (bib[g]+bhb[g]) : (bif[g]+bhf[g]);
  const float* wrow = wl + c*53;
  float acc[32];
#pragma unroll
  for (int r=0;r<32;r++) acc[r]=bias;
#pragma unroll 1
  for (int i0=0; i0<CD; i0+=4) {
    float w0=wrow[i0], w1=wrow[i0+1], w2=wrow[i0+2], w3=wrow[i0+3];
#pragma unroll
    for (int r=0;r<32;r++) {
      float4 a4 = *reinterpret_cast<const float4*>(&al[r*CD + i0]);
      acc[r] += a4.x*w0 + a4.y*w1 + a4.z*w2 + a4.w*w3;
    }
  }
  float* op = xg + (size_t)dir*PD*TD*GD + (size_t)r0*GD + g;
#pragma unroll
  for (int r=0;r<32;r++) op[(size_t)r*GD] = acc[r];
}

// ============ bidirectional LSTM: wave/(seq,dir), full xg slice staged in LDS ============
// 48 KiB LDS per block; recurrence reads via ds_read (1-step LDS prefetch).
__global__ __launch_bounds__(64) void lstm_kernel(
    const float* __restrict__ xg,
    const float* __restrict__ whf, const float* __restrict__ whb,
    float* __restrict__ out, const int mode) {
  __shared__ __align__(16) float xl[TD*GD];   // 49152 B
  const int p = blockIdx.x >> 1;
  const int dir = blockIdx.x & 1;
  const int l = threadIdx.x;
  const float* xp = xg + ((size_t)dir*PD + p)*TD*GD;
  // stage entire slice: 48 chunks x (64 lanes x 16 B) = 49152 B, linear
#pragma unroll 1
  for (int ch = 0; ch < 48; ++ch) {
    __builtin_amdgcn_global_load_lds(
        (const __attribute__((address_space(1))) unsigned int*)(xp + ch*256 + l*4),
        (__attribute__((address_space(3))) unsigned int*)(&xl[ch*256]),
        16, 0, 0);
  }
  const float* wh = dir ? whb : whf;
  const int gA = l;
  const int gB = 64 + (l & 31);
  float wA[HID], wB[HID];
#pragma unroll
  for (int j=0;j<HID;j+=4) {
    float4 a4 = *reinterpret_cast<const float4*>(wh + gA*HID + j);
    wA[j]=a4.x; wA[j+1]=a4.y; wA[j+2]=a4.z; wA[j+3]=a4.w;
    float4 b4 = *reinterpret_cast<const float4*>(wh + gB*HID + j);
    wB[j]=b4.x; wB[j+1]=b4.y; wB[j+2]=b4.z; wB[j+3]=b4.w;
  }
  const bool tA = (gA >= 48);
  const bool tB = ((l & 31) < 8);
  const float saA = tA?2.f:1.f, ssA = tA?2.f:1.f, sbA = tA?-1.f:0.f;
  const float saB = tB?2.f:1.f, ssB = tB?2.f:1.f, sbB = tB?-1.f:0.f;
  float h[HID];
#pragma unroll
  for (int j=0;j<HID;j++) h[j]=0.f;
  float c = 0.f;
  __syncthreads();   // drains the global_load_lds queue
  int t = dir ? TD-1 : 0;
  const int dt = dir ? -1 : 1;
  float xa = xl[t*GD + gA];
  float xb = xl[t*GD + gB];
  for (int s=0; s<TD; ++s) {
    const int tc = (s+1 < TD) ? (t + dt) : t;
    float na = xl[tc*GD + gA];          // LDS prefetch, 1 step ahead
    float nb = xl[tc*GD + gB];
    float pa0=0.f,pa1=0.f,pa2=0.f,pa3=0.f, pb0=0.f,pb1=0.f,pb2=0.f,pb3=0.f;
#pragma unroll
    for (int j=0;j<HID;j+=4) {
      pa0 += wA[j]  *h[j];   pb0 += wB[j]  *h[j];
      pa1 += wA[j+1]*h[j+1]; pb1 += wB[j+1]*h[j+1];
      pa2 += wA[j+2]*h[j+2]; pb2 += wB[j+2]*h[j+2];
      pa3 += wA[j+3]*h[j+3]; pb3 += wB[j+3]*h[j+3];
    }
    float accA = xa + ((pa0+pa1)+(pa2+pa3));
    float accB = xb + ((pb0+pb1)+(pb2+pb3));
    float vA = actg(saA, ssA, sbA, accA);
    float vB = actg(saB, ssB, sbB, accB);
    float f  = __shfl(vA, (24 + l) & 63);
    float g1 = __shfl(vA, (48 + l) & 63);
    float g2 = __shfl(vB, (l - 16) & 63);
    float o  = __shfl(vB, (8 + l) & 63);
    float gg = (l < 16) ? g1 : g2;
    c = f*c + vA*gg;
    float th = 2.f*__builtin_amdgcn_rcpf(1.f + __expf(-2.f*c)) - 1.f;
    float hn = o * th;
    if (l < HID) {
      if (mode==0) out[((size_t)p*TD + t)*CD + dir*HID + l] = hn;
      else         out[((size_t)t*PD + p)*CD + dir*HID + l] = hn;
    }
#pragma unroll
    for (int j=0;j<HID;j++)
      h[j] = __int_as_float(__builtin_amdgcn_readlane(__float_as_int(hn), j));
    xa = na; xb = nb; t = tc;
  }
}

// ============ qkv projection (r4-proven, f32 K/V) ============
__global__ __launch_bounds__(192) void qkv_kernel(
    const float* __restrict__ y, const float* __restrict__ wq,
    const float* __restrict__ bq,
    float* __restrict__ Qb, float* __restrict__ Kb, float* __restrict__ Vb) {
  __shared__ float wl[144*53];
  __shared__ __align__(16) float al[32*CD];
  for (int idx = threadIdx.x; idx < 144*CD; idx += 192) {
    int cc = idx / CD, i = idx - cc*CD;
    wl[cc*53 + i] = wq[idx];
  }
  const int r0 = blockIdx.x * 32;
  for (int idx = threadIdx.x; idx < 32*CD/4; idx += 192)
    reinterpret_cast<float4*>(al)[idx] =
        reinterpret_cast<const float4*>(y + (size_t)r0*CD)[idx];
  __syncthreads();
  const int c = threadIdx.x;
  if (c >= 144) return;
  const float bias = bq[c];
  const float* wrow = wl + c*53;
  float acc[32];
#pragma unroll
  for (int r=0;r<32;r++) acc[r]=bias;
#pragma unroll 1
  for (int i0=0; i0<CD; i0+=4) {
    float w0=wrow[i0], w1=wrow[i0+1], w2=wrow[i0+2], w3=wrow[i0+3];
#pragma unroll
    for (int r=0;r<32;r++) {
      float4 a4 = *reinterpret_cast<const float4*>(&al[r*CD + i0]);
      acc[r] += a4.x*w0 + a4.y*w1 + a4.z*w2 + a4.w*w3;
    }
  }
  float* dst; int col; float sc = 1.f;
  if (c < CD)        { dst = Qb; col = c;      sc = 0.28867513459481287f; }
  else if (c < 2*CD) { dst = Kb; col = c-CD; }
  else               { dst = Vb; col = c-2*CD; }
#pragma unroll
  for (int r=0;r<32;r++) dst[(size_t)(r0+r)*CD + col] = acc[r]*sc;
}

// ============ NATTEN 2D: f32 K/V halo in LDS + bf16 bias table in LDS ============
__global__ __launch_bounds__(256) void natten_kernel(
    const float* __restrict__ Qb, const float* __restrict__ Kb,
    const float* __restrict__ Vb, const float* __restrict__ rpb,
    float* __restrict__ out) {
  __shared__ float kl[NH*400*HDIM];       // 76.8 KB
  __shared__ float vl[NH*400*HDIM];       // 76.8 KB
  __shared__ unsigned short bl[NH*625];   // 5 KB -> total 158.6 KB
  const int tb = blockIdx.x & 15;
  const int wb = blockIdx.x >> 4;
  const int t0 = tb*8, w0 = wb*8;
  const int ht0 = imin(imax(t0-6,0), TD-KW);
  const int hw0 = imin(imax(w0-6,0), PD-KW);
  for (int idx = threadIdx.x; idx < NH*625; idx += 256) bl[idx] = f2bf(rpb[idx]);
  for (int idx = threadIdx.x; idx < 400*HDIM; idx += 256) {
    int pos = idx / HDIM;
    int c4  = idx - pos*HDIM;
    int lw = pos / 20, lt = pos - lw*20;
    int gt = imin(ht0+lt, TD-1), gw = imin(hw0+lw, PD-1);
    int h = c4 / 3, j = c4 - h*3;
    size_t ga = ((size_t)gt*PD + gw)*CD + c4*4;
    *reinterpret_cast<float4*>(&kl[((size_t)h*400+pos)*HDIM + j*4]) =
        *reinterpret_cast<const float4*>(Kb + ga);
    *reinterpret_cast<float4*>(&vl[((size_t)h*400+pos)*HDIM + j*4]) =
        *reinterpret_cast<const float4*>(Vb + ga);
  }
  __syncthreads();
  const int head = threadIdx.x >> 6;
  const int pix  = threadIdx.x & 63;
  const int pt = pix >> 3, pw = pix & 7;
  const int t = t0+pt, w = w0+pw;
  const int ts  = imin(imax(t-6,0), TD-KW);
  const int wsb = imin(imax(w-6,0), PD-KW);
  const int lt0 = ts - ht0, lw0 = wsb - hw0;
  const float* qp = Qb + ((size_t)t*PD + w)*CD + head*HDIM;
  float4 q0 = *reinterpret_cast<const float4*>(qp);
  float4 q1 = *reinterpret_cast<const float4*>(qp+4);
  float4 q2 = *reinterpret_cast<const float4*>(qp+8);
  const float* kb = kl + (size_t)head*4800;
  const float* vb = vl + (size_t)head*4800;
  const unsigned short* bb = bl + head*625 + (ts-t+12)*25 + (wsb-w+12);
  float sum=0.f;
  float o0x=0,o0y=0,o0z=0,o0w=0, o1x=0,o1y=0,o1z=0,o1w=0, o2x=0,o2y=0,o2z=0,o2w=0;
  for (int pp=0; pp<KW; ++pp) {
    const int ltp = lt0+pp;
    const unsigned short* br = bb + pp*25;
    for (int qq=0; qq<KW; ++qq) {
      const int pos = (lw0+qq)*20 + ltp;
      const float* kr = kb + pos*HDIM;
      float4 k0=*reinterpret_cast<const float4*>(kr);
      float4 k1=*reinterpret_cast<const float4*>(kr+4);
      float4 k2=*reinterpret_cast<const float4*>(kr+8);
      float lg = __uint_as_float(((unsigned)br[qq]) << 16);
      lg += q0.x*k0.x + q0.y*k0.y + q0.z*k0.z + q0.w*k0.w;
      lg += q1.x*k1.x + q1.y*k1.y + q1.z*k1.z + q1.w*k1.w;
      lg += q2.x*k2.x + q2.y*k2.y + q2.z*k2.z + q2.w*k2.w;
      float e = __expf(lg);
      sum += e;
      const float* vr = vb + pos*HDIM;
      float4 v0=*reinterpret_cast<const float4*>(vr);
      float4 v1=*reinterpret_cast<const float4*>(vr+4);
      float4 v2=*reinterpret_cast<const float4*>(vr+8);
      o0x += e*v0.x; o0y += e*v0.y; o0z += e*v0.z; o0w += e*v0.w;
      o1x += e*v1.x; o1y += e*v1.y; o1z += e*v1.z; o1w += e*v1.w;
      o2x += e*v2.x; o2y += e*v2.y; o2z += e*v2.z; o2w += e*v2.w;
    }
  }
  float inv = 1.f/sum;
  float* op = out + ((size_t)t*PD + w)*CD + head*HDIM;
  float4 r0v = {o0x*inv,o0y*inv,o0z*inv,o0w*inv};
  float4 r1v = {o1x*inv,o1y*inv,o1z*inv,o1w*inv};
  float4 r2v = {o2x*inv,o2y*inv,o2z*inv,o2w*inv};
  *reinterpret_cast<float4*>(op)   = r0v;
  *reinterpret_cast<float4*>(op+4) = r1v;
  *reinterpret_cast<float4*>(op+8) = r2v;
}

// ============ output projection (r4-proven) ============
__global__ __launch_bounds__(256) void proj_kernel(
    const float* __restrict__ ain, const float* __restrict__ wp,
    const float* __restrict__ bp, float* __restrict__ out) {
  __shared__ float wl[48*53];
  __shared__ __align__(16) float al[32*CD];
  for (int idx = threadIdx.x; idx < CD*CD; idx += 256) {
    int cc = idx / CD, i = idx - cc*CD;
    wl[cc*53 + i] = wp[idx];
  }
  const int r0 = blockIdx.x * 32;
  for (int idx = threadIdx.x; idx < 32*CD/4; idx += 256)
    reinterpret_cast<float4*>(al)[idx] =
        reinterpret_cast<const float4*>(ain + (size_t)r0*CD)[idx];
  __syncthreads();
  const int c  = threadIdx.x & 63;
  const int rg = threadIdx.x >> 6;
  if (c >= CD) return;
  const float bias = bp[c];
  const float* wrow = wl + c*53;
  float acc[8];
#pragma unroll
  for (int r=0;r<8;r++) acc[r]=bias;
#pragma unroll 1
  for (int i0=0; i0<CD; i0+=4) {
    float w0=wrow[i0], w1=wrow[i0+1], w2=wrow[i0+2], w3=wrow[i0+3];
#pragma unroll
    for (int r=0;r<8;r++) {
      float4 a4 = *reinterpret_cast<const float4*>(&al[(rg*8+r)*CD + i0]);
      acc[r] += a4.x*w0 + a4.y*w1 + a4.z*w2 + a4.w*w3;
    }
  }
#pragma unroll
  for (int r=0;r<8;r++) out[(size_t)(r0+rg*8+r)*CD + c] = acc[r];
}

extern "C" void kernel_launch(void* const* d_in, const int* in_sizes, int n_in,
                              void* d_out, int out_size, void* d_ws, size_t ws_size,
                              hipStream_t stream) {
  (void)in_sizes; (void)n_in; (void)out_size; (void)ws_size;
  const float* x        = (const float*)d_in[0];
  const float* w_ih_l0  = (const float*)d_in[1];
  const float* w_hh_l0  = (const float*)d_in[2];
  const float* b_ih_l0  = (const float*)d_in[3];
  const float* b_hh_l0  = (const float*)d_in[4];
  const float* w_ih_l0r = (const float*)d_in[5];
  const float* w_hh_l0r = (const float*)d_in[6];
  const float* b_ih_l0r = (const float*)d_in[7];
  const float* b_hh_l0r = (const float*)d_in[8];
  const float* w_ih_l1  = (const float*)d_in[9];
  const float* w_hh_l1  = (const float*)d_in[10];
  const float* b_ih_l1  = (const float*)d_in[11];
  const float* b_hh_l1  = (const float*)d_in[12];
  const float* w_ih_l1r = (const float*)d_in[13];
  const float* w_hh_l1r = (const float*)d_in[14];
  const float* b_ih_l1r = (const float*)d_in[15];
  const float* b_hh_l1r = (const float*)d_in[16];
  const float* w_qkv    = (const float*)d_in[17];
  const float* b_qkv    = (const float*)d_in[18];
  const float* rpb      = (const float*)d_in[19];
  const float* w_proj   = (const float*)d_in[20];
  const float* b_proj   = (const float*)d_in[21];
  float* out = (float*)d_out;

  float* ws = (float*)d_ws;
  const size_t NPIX = (size_t)TD*PD;
  float* XG = ws;
  float* H0 = XG + (size_t)2*PD*TD*GD;
  float* Y  = H0 + NPIX*CD;
  float* Qb = Y  + NPIX*CD;
  float* Kb = Qb + NPIX*CD;
  float* Vb = Kb + NPIX*CD;
  float* AO = Vb + NPIX*CD;

  xg0_kernel<<<dim3(352,2),384,0,stream>>>(x, w_ih_l0, w_ih_l0r, b_ih_l0, b_hh_l0, b_ih_l0r, b_hh_l0r, XG);
  lstm_kernel<<<2*PD,64,0,stream>>>(XG, w_hh_l0, w_hh_l0r, H0, 0);
  xg1_kernel<<<352,192,0,stream>>>(H0, w_ih_l1, w_ih_l1r, b_ih_l1, b_hh_l1, b_ih_l1r, b_hh_l1r, XG);
  lstm_kernel<<<2*PD,64,0,stream>>>(XG, w_hh_l1, w_hh_l1r, Y, 1);

  for (int l=0; l<2; ++l) {
    qkv_kernel<<<352,192,0,stream>>>(Y, w_qkv, b_qkv, Qb, Kb, Vb);
    natten_kernel<<<176,256,0,stream>>>(Qb, Kb, Vb, rpb, AO);
    proj_kernel<<<352,256,0,stream>>>(AO, w_proj, b_proj, (l==1)? out : Y);
  }
}

// Round 8
// 224.333 us; speedup vs baseline: 1.1516x; 1.1516x over previous
//
#include <hip/hip_runtime.h>

#define PD 88      // sequences == W dim
#define TD 128     // time == T dim
#define I0 133     // layer0 input size
#define HID 24     // LSTM hidden
#define GD 96      // gates = 4*HID
#define CD 48      // channels = 2*HID
#define NH 4       // heads
#define HDIM 12    // head dim
#define KW 13      // neighborhood

__device__ __forceinline__ int imin(int a,int b){return a<b?a:b;}
__device__ __forceinline__ int imax(int a,int b){return a>b?a:b;}

__device__ __forceinline__ float actg(float sa, float ss, float sb, float x) {
  return sa * __builtin_amdgcn_rcpf(1.f + __expf(-ss * x)) + sb;
}
// f32 -> bf16 RTNE
__device__ __forceinline__ unsigned short f2bf(float f) {
  unsigned u = __float_as_uint(f);
  u = u + 0x7fffu + ((u >> 16) & 1u);
  return (unsigned short)(u >> 16);
}

// ============ xg layer0 (r5-proven) ============
__global__ __launch_bounds__(384) void xg0_kernel(
    const float* __restrict__ x,
    const float* __restrict__ wf, const float* __restrict__ wb,
    const float* __restrict__ bif, const float* __restrict__ bhf,
    const float* __restrict__ bib, const float* __restrict__ bhb,
    float* __restrict__ xg) {
  __shared__ __align__(16) float wl[GD*I0];
  __shared__ __align__(16) float al[32*136];
  const int dir = blockIdx.y;
  const float* W = dir ? wb : wf;
  for (int idx = threadIdx.x; idx < GD*I0/4; idx += 384)
    reinterpret_cast<float4*>(wl)[idx] = reinterpret_cast<const float4*>(W)[idx];
  const int r0 = blockIdx.x * 32;
  const int p = r0 >> 7, t0 = r0 & 127;
  for (int idx = threadIdx.x; idx < 32*I0; idx += 384) {
    int r = idx / I0, i = idx - r*I0;
    al[r*136 + i] = x[((size_t)(t0+r)*PD + p)*I0 + i];
  }
  __syncthreads();
  const int c  = threadIdx.x % GD;
  const int rg = threadIdx.x / GD;
  const float bias = (dir ? (bib[c]+bhb[c]) : (bif[c]+bhf[c]));
  float acc[8];
#pragma unroll
  for (int r=0;r<8;r++) acc[r]=bias;
  const float* wrow = wl + c*I0;
  const float* ab = al + rg*8*136;
#pragma unroll 1
  for (int i0=0; i0<132; i0+=4) {
    float w0=wrow[i0], w1=wrow[i0+1], w2=wrow[i0+2], w3=wrow[i0+3];
#pragma unroll
    for (int r=0;r<8;r++) {
      float4 a4 = *reinterpret_cast<const float4*>(&ab[r*136 + i0]);  // broadcast
      acc[r] += a4.x*w0 + a4.y*w1 + a4.z*w2 + a4.w*w3;
    }
  }
  {
    float wlast = wrow[132];
#pragma unroll
    for (int r=0;r<8;r++) acc[r] += ab[r*136 + 132]*wlast;
  }
  float* op = xg + ((size_t)dir*PD*TD + r0 + rg*8)*GD + c;
#pragma unroll
  for (int r=0;r<8;r++) op[(size_t)r*GD] = acc[r];
}

// ============ xg layer1 (r4-proven) ============
__global__ __launch_bounds__(192) void xg1_kernel(
    const float* __restrict__ h0,
    const float* __restrict__ wf, const float* __restrict__ wb,
    const float* __restrict__ bif, const float* __restrict__ bhf,
    const float* __restrict__ bib, const float* __restrict__ bhb,
    float* __restrict__ xg) {
  __shared__ float wl[192*53];
  __shared__ __align__(16) float al[32*CD];
  for (int idx = threadIdx.x; idx < 192*CD; idx += 192) {
    int cc = idx / CD, i = idx - cc*CD;
    wl[cc*53 + i] = (cc < GD) ? wf[cc*CD + i] : wb[(cc-GD)*CD + i];
  }
  const int r0 = blockIdx.x * 32;
  for (int idx = threadIdx.x; idx < 32*CD/4; idx += 192)
    reinterpret_cast<float4*>(al)[idx] =
        reinterpret_cast<const float4*>(h0 + (size_t)r0*CD)[idx];
  __syncthreads();
  const int c = threadIdx.x;
  const int dir = c >= GD;
  const int g = c - dir*GD;
  const float bias = dir ? (bib[g]+bhb[g]) : (bif[g]+bhf[g]);
  const float* wrow = wl + c*53;
  float acc[32];
#pragma unroll
  for (int r=0;r<32;r++) acc[r]=bias;
#pragma unroll 1
  for (int i0=0; i0<CD; i0+=4) {
    float w0=wrow[i0], w1=wrow[i0+1], w2=wrow[i0+2], w3=wrow[i0+3];
#pragma unroll
    for (int r=0;r<32;r++) {
      float4 a4 = *reinterpret_cast<const float4*>(&al[r*CD + i0]);
      acc[r] += a4.x*w0 + a4.y*w1 + a4.z*w2 + a4.w*w3;
    }
  }
  float* op = xg + (size_t)dir*PD*TD*GD + (size_t)r0*GD + g;
#pragma unroll
  for (int r=0;r<32;r++) op[(size_t)r*GD] = acc[r];
}

// ============ bidirectional LSTM: exact 48-lane mapping, 2 bpermutes/step ============
// lanes 0..23: gates i_j (row j), f_j (row 24+j)  [both sigmoid]
// lanes 32..55: gates g_j (row 48+j, tanh), o_j (row 72+j, sigmoid)
// exchange g,o -> low half via 2 ds_bpermute; h broadcast via 24 readlane.
__global__ __launch_bounds__(64) void lstm_kernel(
    const float* __restrict__ xg,
    const float* __restrict__ whf, const float* __restrict__ whb,
    float* __restrict__ out, const int mode) {
  __shared__ __align__(16) float xl[TD*GD];   // 48 KiB
  const int p = blockIdx.x >> 1;
  const int dir = blockIdx.x & 1;
  const int l = threadIdx.x;
  const float* xp = xg + ((size_t)dir*PD + p)*TD*GD;
#pragma unroll 1
  for (int ch = 0; ch < 48; ++ch) {
    __builtin_amdgcn_global_load_lds(
        (const __attribute__((address_space(1))) unsigned int*)(xp + ch*256 + l*4),
        (__attribute__((address_space(3))) unsigned int*)(&xl[ch*256]),
        16, 0, 0);
  }
  const float* wh = dir ? whb : whf;
  const int j = l & 31;
  const bool hi = l >= 32;
  const int r1 = imin(hi ? 48+j : j,    95);   // g : i  (idle lanes clamped)
  const int r2 = imin(hi ? 72+j : 24+j, 95);   // o : f
  float w1[HID], w2[HID];
#pragma unroll
  for (int k=0;k<HID;k+=4) {
    float4 a4 = *reinterpret_cast<const float4*>(wh + r1*HID + k);
    w1[k]=a4.x; w1[k+1]=a4.y; w1[k+2]=a4.z; w1[k+3]=a4.w;
    float4 b4 = *reinterpret_cast<const float4*>(wh + r2*HID + k);
    w2[k]=b4.x; w2[k+1]=b4.y; w2[k+2]=b4.z; w2[k+3]=b4.w;
  }
  // v1: tanh on hi half (g), sigmoid on low (i). v2: sigmoid always (f / o).
  const float sa1 = hi?2.f:1.f, ss1 = hi?2.f:1.f, sb1 = hi?-1.f:0.f;
  float h[HID];
#pragma unroll
  for (int k=0;k<HID;k++) h[k]=0.f;
  float c = 0.f;
  __syncthreads();   // drain global_load_lds
  int t = dir ? TD-1 : 0;
  const int dt = dir ? -1 : 1;
  float* optr = (mode==0) ? out + ((size_t)p*TD + t)*CD + dir*HID + l
                          : out + ((size_t)t*PD + p)*CD + dir*HID + l;
  const ptrdiff_t ostep = (mode==0) ? (ptrdiff_t)dt*CD : (ptrdiff_t)dt*PD*CD;
  const float* xrow = xl + t*GD;
  const ptrdiff_t xstep = (ptrdiff_t)dt*GD;
  const int bpaddr = (32 + j) * 4;   // low lanes pull from lanes 32..55
#pragma unroll 2
  for (int s=0; s<TD; ++s) {
    float x1 = xrow[r1];
    float x2 = xrow[r2];
    float pa0=0.f,pa1=0.f,pa2=0.f,pa3=0.f, pb0=0.f,pb1=0.f,pb2=0.f,pb3=0.f;
#pragma unroll
    for (int k=0;k<HID;k+=4) {
      pa0 += w1[k]  *h[k];   pb0 += w2[k]  *h[k];
      pa1 += w1[k+1]*h[k+1]; pb1 += w2[k+1]*h[k+1];
      pa2 += w1[k+2]*h[k+2]; pb2 += w2[k+2]*h[k+2];
      pa3 += w1[k+3]*h[k+3]; pb3 += w2[k+3]*h[k+3];
    }
    float acc1 = x1 + ((pa0+pa1)+(pa2+pa3));
    float acc2 = x2 + ((pb0+pb1)+(pb2+pb3));
    float v1 = actg(sa1, ss1, sb1, acc1);
    float v2 = __builtin_amdgcn_rcpf(1.f + __expf(-acc2));
    float gg = __int_as_float(__builtin_amdgcn_ds_bpermute(bpaddr, __float_as_int(v1)));
    float oo = __int_as_float(__builtin_amdgcn_ds_bpermute(bpaddr, __float_as_int(v2)));
    c = v2*c + v1*gg;                      // low lanes: f*c + i*g
    float th = 2.f*__builtin_amdgcn_rcpf(1.f + __expf(-2.f*c)) - 1.f;
    float hn = oo * th;
    if (l < HID) *optr = hn;
#pragma unroll
    for (int k=0;k<HID;k++)
      h[k] = __int_as_float(__builtin_amdgcn_readlane(__float_as_int(hn), k));
    optr += ostep; xrow += xstep;
  }
}

// ============ qkv projection (r4-proven) ============
__global__ __launch_bounds__(192) void qkv_kernel(
    const float* __restrict__ y, const float* __restrict__ wq,
    const float* __restrict__ bq,
    float* __restrict__ Qb, float* __restrict__ Kb, float* __restrict__ Vb) {
  __shared__ float wl[144*53];
  __shared__ __align__(16) float al[32*CD];
  for (int idx = threadIdx.x; idx < 144*CD; idx += 192) {
    int cc = idx / CD, i = idx - cc*CD;
    wl[cc*53 + i] = wq[idx];
  }
  const int r0 = blockIdx.x * 32;
  for (int idx = threadIdx.x; idx < 32*CD/4; idx += 192)
    reinterpret_cast<float4*>(al)[idx] =
        reinterpret_cast<const float4*>(y + (size_t)r0*CD)[idx];
  __syncthreads();
  const int c = threadIdx.x;
  if (c >= 144) return;
  const float bias = bq[c];
  const float* wrow = wl + c*53;
  float acc[32];
#pragma unroll
  for (int r=0;r<32;r++) acc[r]=bias;
#pragma unroll 1
  for (int i0=0; i0<CD; i0+=4) {
    float w0=wrow[i0], w1=wrow[i0+1], w2=wrow[i0+2], w3=wrow[i0+3];
#pragma unroll
    for (int r=0;r<32;r++) {
      float4 a4 = *reinterpret_cast<const float4*>(&al[r*CD + i0]);
      acc[r] += a4.x*w0 + a4.y*w1 + a4.z*w2 + a4.w*w3;
    }
  }
  float* dst; int col; float sc = 1.f;
  if (c < CD)        { dst = Qb; col = c;      sc = 0.28867513459481287f; }
  else if (c < 2*CD) { dst = Kb; col = c-CD; }
  else               { dst = Vb; col = c-2*CD; }
#pragma unroll
  for (int r=0;r<32;r++) dst[(size_t)(r0+r)*CD + col] = acc[r]*sc;
}

// ============ NATTEN 2D: 512 thr (8 waves), lane-pair neighbor split ============
__global__ __launch_bounds__(512) void natten_kernel(
    const float* __restrict__ Qb, const float* __restrict__ Kb,
    const float* __restrict__ Vb, const float* __restrict__ rpb,
    float* __restrict__ out) {
  __shared__ float kl[NH*400*HDIM];       // 76.8 KB
  __shared__ float vl[NH*400*HDIM];       // 76.8 KB
  __shared__ unsigned short bl[NH*625];   // 5 KB
  const int tb = blockIdx.x & 15;
  const int wb = blockIdx.x >> 4;
  const int t0 = tb*8, w0 = wb*8;
  const int ht0 = imin(imax(t0-6,0), TD-KW);
  const int hw0 = imin(imax(w0-6,0), PD-KW);
  for (int idx = threadIdx.x; idx < NH*625; idx += 512) bl[idx] = f2bf(rpb[idx]);
  for (int idx = threadIdx.x; idx < 400*HDIM; idx += 512) {
    int pos = idx / HDIM;
    int c4  = idx - pos*HDIM;
    int lw = pos / 20, lt = pos - lw*20;
    int gt = imin(ht0+lt, TD-1), gw = imin(hw0+lw, PD-1);
    int h = c4 / 3, jj = c4 - h*3;
    size_t ga = ((size_t)gt*PD + gw)*CD + c4*4;
    *reinterpret_cast<float4*>(&kl[((size_t)h*400+pos)*HDIM + jj*4]) =
        *reinterpret_cast<const float4*>(Kb + ga);
    *reinterpret_cast<float4*>(&vl[((size_t)h*400+pos)*HDIM + jj*4]) =
        *reinterpret_cast<const float4*>(Vb + ga);
  }
  __syncthreads();
  const int wv   = threadIdx.x >> 6;      // 0..7
  const int head = wv >> 1;
  const int lane = threadIdx.x & 63;
  const int e    = lane & 1;              // neighbor-column parity
  const int pixidx = (wv & 1)*32 + (lane >> 1);   // 0..63
  const int pt = pixidx >> 3, pw = pixidx & 7;
  const int t = t0+pt, w = w0+pw;
  const int ts  = imin(imax(t-6,0), TD-KW);
  const int wsb = imin(imax(w-6,0), PD-KW);
  const int lt0 = ts - ht0, lw0 = wsb - hw0;
  const float* qp = Qb + ((size_t)t*PD + w)*CD + head*HDIM;
  float4 q0 = *reinterpret_cast<const float4*>(qp);
  float4 q1 = *reinterpret_cast<const float4*>(qp+4);
  float4 q2 = *reinterpret_cast<const float4*>(qp+8);
  const float* kb = kl + (size_t)head*4800;
  const float* vb = vl + (size_t)head*4800;
  const unsigned short* bb = bl + head*625 + (ts-t+12)*25 + (wsb-w+12);
  float sum=0.f;
  float o0x=0,o0y=0,o0z=0,o0w=0, o1x=0,o1y=0,o1z=0,o1w=0, o2x=0,o2y=0,o2z=0,o2w=0;
  for (int pp=0; pp<KW; ++pp) {
    const int ltp = lt0+pp;
    const unsigned short* br = bb + pp*25;
#pragma unroll 1
    for (int qq=e; qq<KW; qq+=2) {       // even lanes: 0,2,..,12; odd: 1,3,..,11
      const int pos = (lw0+qq)*20 + ltp;
      const float* kr = kb + pos*HDIM;
      float4 k0=*reinterpret_cast<const float4*>(kr);
      float4 k1=*reinterpret_cast<const float4*>(kr+4);
      float4 k2=*reinterpret_cast<const float4*>(kr+8);
      float lg = __uint_as_float(((unsigned)br[qq]) << 16);
      lg += q0.x*k0.x + q0.y*k0.y + q0.z*k0.z + q0.w*k0.w;
      lg += q1.x*k1.x + q1.y*k1.y + q1.z*k1.z + q1.w*k1.w;
      lg += q2.x*k2.x + q2.y*k2.y + q2.z*k2.z + q2.w*k2.w;
      float ee = __expf(lg);
      sum += ee;
      const float* vr = vb + pos*HDIM;
      float4 v0=*reinterpret_cast<const float4*>(vr);
      float4 v1=*reinterpret_cast<const float4*>(vr+4);
      float4 v2=*reinterpret_cast<const float4*>(vr+8);
      o0x += ee*v0.x; o0y += ee*v0.y; o0z += ee*v0.z; o0w += ee*v0.w;
      o1x += ee*v1.x; o1y += ee*v1.y; o1z += ee*v1.z; o1w += ee*v1.w;
      o2x += ee*v2.x; o2y += ee*v2.y; o2z += ee*v2.z; o2w += ee*v2.w;
    }
  }
  // combine the lane pair (xor-1 = DPP, no LDS)
  sum += __shfl_xor(sum, 1);
  o0x += __shfl_xor(o0x,1); o0y += __shfl_xor(o0y,1);
  o0z += __shfl_xor(o0z,1); o0w += __shfl_xor(o0w,1);
  o1x += __shfl_xor(o1x,1); o1y += __shfl_xor(o1y,1);
  o1z += __shfl_xor(o1z,1); o1w += __shfl_xor(o1w,1);
  o2x += __shfl_xor(o2x,1); o2y += __shfl_xor(o2y,1);
  o2z += __shfl_xor(o2z,1); o2w += __shfl_xor(o2w,1);
  if (e == 0) {
    float inv = 1.f/sum;
    float* op = out + ((size_t)t*PD + w)*CD + head*HDIM;
    float4 r0v = {o0x*inv,o0y*inv,o0z*inv,o0w*inv};
    float4 r1v = {o1x*inv,o1y*inv,o1z*inv,o1w*inv};
    float4 r2v = {o2x*inv,o2y*inv,o2z*inv,o2w*inv};
    *reinterpret_cast<float4*>(op)   = r0v;
    *reinterpret_cast<float4*>(op+4) = r1v;
    *reinterpret_cast<float4*>(op+8) = r2v;
  }
}

// ============ output projection (r4-proven) ============
__global__ __launch_bounds__(256) void proj_kernel(
    const float* __restrict__ ain, const float* __restrict__ wp,
    const float* __restrict__ bp, float* __restrict__ out) {
  __shared__ float wl[48*53];
  __shared__ __align__(16) float al[32*CD];
  for (int idx = threadIdx.x; idx < CD*CD; idx += 256) {
    int cc = idx / CD, i = idx - cc*CD;
    wl[cc*53 + i] = wp[idx];
  }
  const int r0 = blockIdx.x * 32;
  for (int idx = threadIdx.x; idx < 32*CD/4; idx += 256)
    reinterpret_cast<float4*>(al)[idx] =
        reinterpret_cast<const float4*>(ain + (size_t)r0*CD)[idx];
  __syncthreads();
  const int c  = threadIdx.x & 63;
  const int rg = threadIdx.x >> 6;
  if (c >= CD) return;
  const float bias = bp[c];
  const float* wrow = wl + c*53;
  float acc[8];
#pragma unroll
  for (int r=0;r<8;r++) acc[r]=bias;
#pragma unroll 1
  for (int i0=0; i0<CD; i0+=4) {
    float w0=wrow[i0], w1=wrow[i0+1], w2=wrow[i0+2], w3=wrow[i0+3];
#pragma unroll
    for (int r=0;r<8;r++) {
      float4 a4 = *reinterpret_cast<const float4*>(&al[(rg*8+r)*CD + i0]);
      acc[r] += a4.x*w0 + a4.y*w1 + a4.z*w2 + a4.w*w3;
    }
  }
#pragma unroll
  for (int r=0;r<8;r++) out[(size_t)(r0+rg*8+r)*CD + c] = acc[r];
}

extern "C" void kernel_launch(void* const* d_in, const int* in_sizes, int n_in,
                              void* d_out, int out_size, void* d_ws, size_t ws_size,
                              hipStream_t stream) {
  (void)in_sizes; (void)n_in; (void)out_size; (void)ws_size;
  const float* x        = (const float*)d_in[0];
  const float* w_ih_l0  = (const float*)d_in[1];
  const float* w_hh_l0  = (const float*)d_in[2];
  const float* b_ih_l0  = (const float*)d_in[3];
  const float* b_hh_l0  = (const float*)d_in[4];
  const float* w_ih_l0r = (const float*)d_in[5];
  const float* w_hh_l0r = (const float*)d_in[6];
  const float* b_ih_l0r = (const float*)d_in[7];
  const float* b_hh_l0r = (const float*)d_in[8];
  const float* w_ih_l1  = (const float*)d_in[9];
  const float* w_hh_l1  = (const float*)d_in[10];
  const float* b_ih_l1  = (const float*)d_in[11];
  const float* b_hh_l1  = (const float*)d_in[12];
  const float* w_ih_l1r = (const float*)d_in[13];
  const float* w_hh_l1r = (const float*)d_in[14];
  const float* b_ih_l1r = (const float*)d_in[15];
  const float* b_hh_l1r = (const float*)d_in[16];
  const float* w_qkv    = (const float*)d_in[17];
  const float* b_qkv    = (const float*)d_in[18];
  const float* rpb      = (const float*)d_in[19];
  const float* w_proj   = (const float*)d_in[20];
  const float* b_proj   = (const float*)d_in[21];
  float* out = (float*)d_out;

  float* ws = (float*)d_ws;
  const size_t NPIX = (size_t)TD*PD;
  float* XG = ws;
  float* H0 = XG + (size_t)2*PD*TD*GD;
  float* Y  = H0 + NPIX*CD;
  float* Qb = Y  + NPIX*CD;
  float* Kb = Qb + NPIX*CD;
  float* Vb = Kb + NPIX*CD;
  float* AO = Vb + NPIX*CD;

  xg0_kernel<<<dim3(352,2),384,0,stream>>>(x, w_ih_l0, w_ih_l0r, b_ih_l0, b_hh_l0, b_ih_l0r, b_hh_l0r, XG);
  lstm_kernel<<<2*PD,64,0,stream>>>(XG, w_hh_l0, w_hh_l0r, H0, 0);
  xg1_kernel<<<352,192,0,stream>>>(H0, w_ih_l1, w_ih_l1r, b_ih_l1, b_hh_l1, b_ih_l1r, b_hh_l1r, XG);
  lstm_kernel<<<2*PD,64,0,stream>>>(XG, w_hh_l1, w_hh_l1r, Y, 1);

  for (int l=0; l<2; ++l) {
    qkv_kernel<<<352,192,0,stream>>>(Y, w_qkv, b_qkv, Qb, Kb, Vb);
    natten_kernel<<<176,512,0,stream>>>(Qb, Kb, Vb, rpb, AO);
    proj_kernel<<<352,256,0,stream>>>(AO, w_proj, b_proj, (l==1)? out : Y);
  }
}

// Round 9
// 221.721 us; speedup vs baseline: 1.1651x; 1.0118x over previous
//
#include <hip/hip_runtime.h>

#define PD 88      // sequences == W dim
#define TD 128     // time == T dim
#define I0 133     // layer0 input size
#define HID 24     // LSTM hidden
#define GD 96      // gates = 4*HID
#define CD 48      // channels = 2*HID
#define NH 4       // heads
#define HDIM 12    // head dim
#define KW 13      // neighborhood

__device__ __forceinline__ int imin(int a,int b){return a<b?a:b;}
__device__ __forceinline__ int imax(int a,int b){return a>b?a:b;}

__device__ __forceinline__ float actg(float sa, float ss, float sb, float x) {
  return sa * __builtin_amdgcn_rcpf(1.f + __expf(-ss * x)) + sb;
}
// f32 -> bf16 RTNE
__device__ __forceinline__ unsigned short f2bf(float f) {
  unsigned u = __float_as_uint(f);
  u = u + 0x7fffu + ((u >> 16) & 1u);
  return (unsigned short)(u >> 16);
}
#define BLO(u) __uint_as_float((u) << 16)
#define BHI(u) __uint_as_float((u) & 0xffff0000u)

// ============ xg layer0 v3: 4 cols x 8 rows per thread, transposed weights ============
// block 192 = (cg 0..23) x (rg 0..7); 64-row tile; weights wt[k][col] pad 104.
// Per k4-chunk per wave: 4 w-b128 + 8 a-b128 feed 256 VALU cyc -> VALU-bound.
__global__ __launch_bounds__(192) void xg0_kernel(
    const float* __restrict__ x,
    const float* __restrict__ wf, const float* __restrict__ wb,
    const float* __restrict__ bif, const float* __restrict__ bhf,
    const float* __restrict__ bib, const float* __restrict__ bhb,
    float* __restrict__ xg) {
  __shared__ __align__(16) float wt[I0*104];  // 55.3 KB transposed [133][96 pad 104]
  __shared__ __align__(16) float al[64*136];  // 34.8 KB
  const int dir = blockIdx.y;
  const float* W = dir ? wb : wf;
  for (int idx = threadIdx.x; idx < GD*I0; idx += 192) {
    int g = idx / I0, i = idx - g*I0;
    wt[i*104 + g] = W[idx];
  }
  const int r0 = blockIdx.x * 64;            // 64 | 128 -> same p
  const int p = r0 >> 7, t0 = r0 & 127;
  for (int idx = threadIdx.x; idx < 64*I0; idx += 192) {
    int r = idx / I0, i = idx - r*I0;
    al[r*136 + i] = x[((size_t)(t0+r)*PD + p)*I0 + i];
  }
  __syncthreads();
  const int cg = threadIdx.x % 24;
  const int rg = threadIdx.x / 24;           // 0..7
  const int c0 = cg*4;
  const float* bi = dir ? bib : bif;
  const float* bh = dir ? bhb : bhf;
  float4 bias;
  bias.x = bi[c0]   + bh[c0];
  bias.y = bi[c0+1] + bh[c0+1];
  bias.z = bi[c0+2] + bh[c0+2];
  bias.w = bi[c0+3] + bh[c0+3];
  float4 acc[8];
#pragma unroll
  for (int r=0;r<8;r++) acc[r] = bias;
  const float* ab = al + rg*8*136;
#pragma unroll 1
  for (int i0=0; i0<132; i0+=4) {
    float4 w0 = *reinterpret_cast<const float4*>(&wt[(i0+0)*104 + c0]);
    float4 w1 = *reinterpret_cast<const float4*>(&wt[(i0+1)*104 + c0]);
    float4 w2 = *reinterpret_cast<const float4*>(&wt[(i0+2)*104 + c0]);
    float4 w3 = *reinterpret_cast<const float4*>(&wt[(i0+3)*104 + c0]);
#pragma unroll
    for (int r=0;r<8;r++) {
      float4 a = *reinterpret_cast<const float4*>(&ab[r*136 + i0]);
      acc[r].x += a.x*w0.x + a.y*w1.x + a.z*w2.x + a.w*w3.x;
      acc[r].y += a.x*w0.y + a.y*w1.y + a.z*w2.y + a.w*w3.y;
      acc[r].z += a.x*w0.z + a.y*w1.z + a.z*w2.z + a.w*w3.z;
      acc[r].w += a.x*w0.w + a.y*w1.w + a.z*w2.w + a.w*w3.w;
    }
  }
  {
    float4 wl4 = *reinterpret_cast<const float4*>(&wt[132*104 + c0]);
#pragma unroll
    for (int r=0;r<8;r++) {
      float av = ab[r*136 + 132];
      acc[r].x += av*wl4.x; acc[r].y += av*wl4.y;
      acc[r].z += av*wl4.z; acc[r].w += av*wl4.w;
    }
  }
  float* op = xg + ((size_t)dir*PD*TD + r0 + rg*8)*GD + c0;
#pragma unroll
  for (int r=0;r<8;r++)
    *reinterpret_cast<float4*>(op + (size_t)r*GD) = acc[r];
}

// ============ xg layer1 (r4-proven) ============
__global__ __launch_bounds__(192) void xg1_kernel(
    const float* __restrict__ h0,
    const float* __restrict__ wf, const float* __restrict__ wb,
    const float* __restrict__ bif, const float* __restrict__ bhf,
    const float* __restrict__ bib, const float* __restrict__ bhb,
    float* __restrict__ xg) {
  __shared__ float wl[192*53];
  __shared__ __align__(16) float al[32*CD];
  for (int idx = threadIdx.x; idx < 192*CD; idx += 192) {
    int cc = idx / CD, i = idx - cc*CD;
    wl[cc*53 + i] = (cc < GD) ? wf[cc*CD + i] : wb[(cc-GD)*CD + i];
  }
  const int r0 = blockIdx.x * 32;
  for (int idx = threadIdx.x; idx < 32*CD/4; idx += 192)
    reinterpret_cast<float4*>(al)[idx] =
        reinterpret_cast<const float4*>(h0 + (size_t)r0*CD)[idx];
  __syncthreads();
  const int c = threadIdx.x;
  const int dir = c >= GD;
  const int g = c - dir*GD;
  const float bias = dir ? (bib[g]+bhb[g]) : (bif[g]+bhf[g]);
  const float* wrow = wl + c*53;
  float acc[32];
#pragma unroll
  for (int r=0;r<32;r++) acc[r]=bias;
#pragma unroll 1
  for (int i0=0; i0<CD; i0+=4) {
    float w0=wrow[i0], w1=wrow[i0+1], w2=wrow[i0+2], w3=wrow[i0+3];
#pragma unroll
    for (int r=0;r<32;r++) {
      float4 a4 = *reinterpret_cast<const float4*>(&al[r*CD + i0]);
      acc[r] += a4.x*w0 + a4.y*w1 + a4.z*w2 + a4.w*w3;
    }
  }
  float* op = xg + (size_t)dir*PD*TD*GD + (size_t)r0*GD + g;
#pragma unroll
  for (int r=0;r<32;r++) op[(size_t)r*GD] = acc[r];
}

// ============ bidirectional LSTM (r8 structure + LDS prefetch + unroll 4) ============
__global__ __launch_bounds__(64) void lstm_kernel(
    const float* __restrict__ xg,
    const float* __restrict__ whf, const float* __restrict__ whb,
    float* __restrict__ out, const int mode) {
  __shared__ __align__(16) float xl[TD*GD];   // 48 KiB
  const int p = blockIdx.x >> 1;
  const int dir = blockIdx.x & 1;
  const int l = threadIdx.x;
  const float* xp = xg + ((size_t)dir*PD + p)*TD*GD;
#pragma unroll 1
  for (int ch = 0; ch < 48; ++ch) {
    __builtin_amdgcn_global_load_lds(
        (const __attribute__((address_space(1))) unsigned int*)(xp + ch*256 + l*4),
        (__attribute__((address_space(3))) unsigned int*)(&xl[ch*256]),
        16, 0, 0);
  }
  const float* wh = dir ? whb : whf;
  const int j = l & 31;
  const bool hi = l >= 32;
  const int r1 = imin(hi ? 48+j : j,    95);
  const int r2 = imin(hi ? 72+j : 24+j, 95);
  float w1[HID], w2[HID];
#pragma unroll
  for (int k=0;k<HID;k+=4) {
    float4 a4 = *reinterpret_cast<const float4*>(wh + r1*HID + k);
    w1[k]=a4.x; w1[k+1]=a4.y; w1[k+2]=a4.z; w1[k+3]=a4.w;
    float4 b4 = *reinterpret_cast<const float4*>(wh + r2*HID + k);
    w2[k]=b4.x; w2[k+1]=b4.y; w2[k+2]=b4.z; w2[k+3]=b4.w;
  }
  const float sa1 = hi?2.f:1.f, ss1 = hi?2.f:1.f, sb1 = hi?-1.f:0.f;
  float h[HID];
#pragma unroll
  for (int k=0;k<HID;k++) h[k]=0.f;
  float c = 0.f;
  __syncthreads();
  int t = dir ? TD-1 : 0;
  const int dt = dir ? -1 : 1;
  float* optr = (mode==0) ? out + ((size_t)p*TD + t)*CD + dir*HID + l
                          : out + ((size_t)t*PD + p)*CD + dir*HID + l;
  const ptrdiff_t ostep = (mode==0) ? (ptrdiff_t)dt*CD : (ptrdiff_t)dt*PD*CD;
  const float* xrow = xl + t*GD;
  const ptrdiff_t xstep = (ptrdiff_t)dt*GD;
  const int bpaddr = (32 + j) * 4;
  float x1 = xrow[r1];
  float x2 = xrow[r2];
#pragma unroll 4
  for (int s=0; s<TD; ++s) {
    // prefetch next step (last-iter read is harmlessly OOB-in-LDS, value unused)
    float n1 = xrow[xstep + r1];
    float n2 = xrow[xstep + r2];
    float pa0=0.f,pa1=0.f,pa2=0.f,pa3=0.f, pb0=0.f,pb1=0.f,pb2=0.f,pb3=0.f;
#pragma unroll
    for (int k=0;k<HID;k+=4) {
      pa0 += w1[k]  *h[k];   pb0 += w2[k]  *h[k];
      pa1 += w1[k+1]*h[k+1]; pb1 += w2[k+1]*h[k+1];
      pa2 += w1[k+2]*h[k+2]; pb2 += w2[k+2]*h[k+2];
      pa3 += w1[k+3]*h[k+3]; pb3 += w2[k+3]*h[k+3];
    }
    float acc1 = x1 + ((pa0+pa1)+(pa2+pa3));
    float acc2 = x2 + ((pb0+pb1)+(pb2+pb3));
    float v1 = actg(sa1, ss1, sb1, acc1);
    float v2 = __builtin_amdgcn_rcpf(1.f + __expf(-acc2));
    float gg = __int_as_float(__builtin_amdgcn_ds_bpermute(bpaddr, __float_as_int(v1)));
    float oo = __int_as_float(__builtin_amdgcn_ds_bpermute(bpaddr, __float_as_int(v2)));
    c = v2*c + v1*gg;
    float th = 2.f*__builtin_amdgcn_rcpf(1.f + __expf(-2.f*c)) - 1.f;
    float hn = oo * th;
    if (l < HID) *optr = hn;
#pragma unroll
    for (int k=0;k<HID;k++)
      h[k] = __int_as_float(__builtin_amdgcn_readlane(__float_as_int(hn), k));
    optr += ostep; xrow += xstep;
    x1 = n1; x2 = n2;
  }
}

// ============ qkv projection: Q f32 (scaled), K/V bf16 packed [pix][4 heads][16] ============
__global__ __launch_bounds__(192) void qkv_kernel(
    const float* __restrict__ y, const float* __restrict__ wq,
    const float* __restrict__ bq,
    float* __restrict__ Qb, unsigned short* __restrict__ Kb,
    unsigned short* __restrict__ Vb) {
  __shared__ float wl[144*53];
  __shared__ __align__(16) float al[32*CD];
  for (int idx = threadIdx.x; idx < 144*CD; idx += 192) {
    int cc = idx / CD, i = idx - cc*CD;
    wl[cc*53 + i] = wq[idx];
  }
  const int r0 = blockIdx.x * 32;
  for (int idx = threadIdx.x; idx < 32*CD/4; idx += 192)
    reinterpret_cast<float4*>(al)[idx] =
        reinterpret_cast<const float4*>(y + (size_t)r0*CD)[idx];
  __syncthreads();
  const int c = threadIdx.x;
  if (c >= 144) return;
  const float bias = bq[c];
  const float* wrow = wl + c*53;
  float acc[32];
#pragma unroll
  for (int r=0;r<32;r++) acc[r]=bias;
#pragma unroll 1
  for (int i0=0; i0<CD; i0+=4) {
    float w0=wrow[i0], w1=wrow[i0+1], w2=wrow[i0+2], w3=wrow[i0+3];
#pragma unroll
    for (int r=0;r<32;r++) {
      float4 a4 = *reinterpret_cast<const float4*>(&al[r*CD + i0]);
      acc[r] += a4.x*w0 + a4.y*w1 + a4.z*w2 + a4.w*w3;
    }
  }
  if (c < CD) {
#pragma unroll
    for (int r=0;r<32;r++)
      Qb[(size_t)(r0+r)*CD + c] = acc[r]*0.28867513459481287f;
  } else if (c < 2*CD) {
    int cc = c - CD, head = cc / HDIM, jj = cc - head*HDIM;
#pragma unroll
    for (int r=0;r<32;r++)
      Kb[(size_t)(r0+r)*64 + head*16 + jj] = f2bf(acc[r]);
  } else {
    int cc = c - 2*CD, head = cc / HDIM, jj = cc - head*HDIM;
#pragma unroll
    for (int r=0;r<32;r++)
      Vb[(size_t)(r0+r)*64 + head*16 + jj] = f2bf(acc[r]);
  }
}

// ============ NATTEN 2D: bf16 K/V (24B rows), pt-fast lanes, 8 waves, pair-split ============
__global__ __launch_bounds__(512) void natten_kernel(
    const float* __restrict__ Qb, const unsigned short* __restrict__ Kb,
    const unsigned short* __restrict__ Vb, const float* __restrict__ rpb,
    float* __restrict__ out) {
  __shared__ __align__(8) unsigned kl[NH*400*6];   // 38.4 KB (12 bf16 per pos)
  __shared__ __align__(8) unsigned vl[NH*400*6];   // 38.4 KB
  __shared__ unsigned short bl[NH*625];            // 5 KB
  const int tb = blockIdx.x & 15;
  const int wb = blockIdx.x >> 4;
  const int t0 = tb*8, w0 = wb*8;
  const int ht0 = imin(imax(t0-6,0), TD-KW);
  const int hw0 = imin(imax(w0-6,0), PD-KW);
  for (int idx = threadIdx.x; idx < NH*625; idx += 512) bl[idx] = f2bf(rpb[idx]);
  for (int idx = threadIdx.x; idx < NH*400; idx += 512) {
    int h = idx / 400, pos = idx - h*400;
    int lw = pos / 20, lt = pos - lw*20;
    int gt = imin(ht0+lt, TD-1), gw = imin(hw0+lw, PD-1);
    size_t gb = ((size_t)gt*PD + gw)*64 + h*16;    // ushort units, 8B-aligned
    const uint2* kg = reinterpret_cast<const uint2*>(Kb + gb);
    const uint2* vg = reinterpret_cast<const uint2*>(Vb + gb);
    unsigned* kd = kl + idx*6;
    unsigned* vd = vl + idx*6;
    *reinterpret_cast<uint2*>(kd)   = kg[0];
    *reinterpret_cast<uint2*>(kd+2) = kg[1];
    *reinterpret_cast<uint2*>(kd+4) = kg[2];
    *reinterpret_cast<uint2*>(vd)   = vg[0];
    *reinterpret_cast<uint2*>(vd+2) = vg[1];
    *reinterpret_cast<uint2*>(vd+4) = vg[2];
  }
  __syncthreads();
  const int wv   = threadIdx.x >> 6;      // 0..7
  const int head = wv >> 1;
  const int lane = threadIdx.x & 63;
  const int e    = lane & 1;              // neighbor-column parity
  const int pixidx = (wv & 1)*32 + (lane >> 1);
  const int pt = pixidx & 7, pw = pixidx >> 3;   // pt-fast: adjacent lanes -> pos+1
  const int t = t0+pt, w = w0+pw;
  const int ts  = imin(imax(t-6,0), TD-KW);
  const int wsb = imin(imax(w-6,0), PD-KW);
  const int lt0 = ts - ht0, lw0 = wsb - hw0;
  const float* qp = Qb + ((size_t)t*PD + w)*CD + head*HDIM;
  float4 q0 = *reinterpret_cast<const float4*>(qp);
  float4 q1 = *reinterpret_cast<const float4*>(qp+4);
  float4 q2 = *reinterpret_cast<const float4*>(qp+8);
  const unsigned* kbp = kl + head*2400;
  const unsigned* vbp = vl + head*2400;
  const unsigned short* bb = bl + head*625 + (ts-t+12)*25 + (wsb-w+12);
  float sum=0.f;
  float o0=0,o1=0,o2=0,o3=0,o4=0,o5=0,o6=0,o7=0,o8=0,o9=0,o10=0,o11=0;
  for (int pp=0; pp<KW; ++pp) {
    const int ltp = lt0+pp;
    const unsigned short* br = bb + pp*25;
#pragma unroll 1
    for (int qq=e; qq<KW; qq+=2) {
      const int pos = (lw0+qq)*20 + ltp;
      const unsigned* kr = kbp + pos*6;
      uint2 ka = *reinterpret_cast<const uint2*>(kr);
      uint2 kb2= *reinterpret_cast<const uint2*>(kr+2);
      uint2 kc = *reinterpret_cast<const uint2*>(kr+4);
      float lg = __uint_as_float(((unsigned)br[qq]) << 16);
      lg += q0.x*BLO(ka.x) + q0.y*BHI(ka.x)
          + q0.z*BLO(ka.y) + q0.w*BHI(ka.y)
          + q1.x*BLO(kb2.x)+ q1.y*BHI(kb2.x)
          + q1.z*BLO(kb2.y)+ q1.w*BHI(kb2.y)
          + q2.x*BLO(kc.x) + q2.y*BHI(kc.x)
          + q2.z*BLO(kc.y) + q2.w*BHI(kc.y);
      float ex = __expf(lg);
      sum += ex;
      const unsigned* vr = vbp + pos*6;
      uint2 va = *reinterpret_cast<const uint2*>(vr);
      uint2 vb2= *reinterpret_cast<const uint2*>(vr+2);
      uint2 vc = *reinterpret_cast<const uint2*>(vr+4);
      o0  += ex*BLO(va.x);  o1  += ex*BHI(va.x);
      o2  += ex*BLO(va.y);  o3  += ex*BHI(va.y);
      o4  += ex*BLO(vb2.x); o5  += ex*BHI(vb2.x);
      o6  += ex*BLO(vb2.y); o7  += ex*BHI(vb2.y);
      o8  += ex*BLO(vc.x);  o9  += ex*BHI(vc.x);
      o10 += ex*BLO(vc.y);  o11 += ex*BHI(vc.y);
    }
  }
  sum += __shfl_xor(sum, 1);
  o0 += __shfl_xor(o0,1);  o1 += __shfl_xor(o1,1);
  o2 += __shfl_xor(o2,1);  o3 += __shfl_xor(o3,1);
  o4 += __shfl_xor(o4,1);  o5 += __shfl_xor(o5,1);
  o6 += __shfl_xor(o6,1);  o7 += __shfl_xor(o7,1);
  o8 += __shfl_xor(o8,1);  o9 += __shfl_xor(o9,1);
  o10 += __shfl_xor(o10,1);o11 += __shfl_xor(o11,1);
  if (e == 0) {
    float inv = 1.f/sum;
    float* op = out + ((size_t)t*PD + w)*CD + head*HDIM;
    float4 r0v = {o0*inv,o1*inv,o2*inv,o3*inv};
    float4 r1v = {o4*inv,o5*inv,o6*inv,o7*inv};
    float4 r2v = {o8*inv,o9*inv,o10*inv,o11*inv};
    *reinterpret_cast<float4*>(op)   = r0v;
    *reinterpret_cast<float4*>(op+4) = r1v;
    *reinterpret_cast<float4*>(op+8) = r2v;
  }
}

// ============ output projection (r4-proven) ============
__global__ __launch_bounds__(256) void proj_kernel(
    const float* __restrict__ ain, const float* __restrict__ wp,
    const float* __restrict__ bp, float* __restrict__ out) {
  __shared__ float wl[48*53];
  __shared__ __align__(16) float al[32*CD];
  for (int idx = threadIdx.x; idx < CD*CD; idx += 256) {
    int cc = idx / CD, i = idx - cc*CD;
    wl[cc*53 + i] = wp[idx];
  }
  const int r0 = blockIdx.x * 32;
  for (int idx = threadIdx.x; idx < 32*CD/4; idx += 256)
    reinterpret_cast<float4*>(al)[idx] =
        reinterpret_cast<const float4*>(ain + (size_t)r0*CD)[idx];
  __syncthreads();
  const int c  = threadIdx.x & 63;
  const int rg = threadIdx.x >> 6;
  if (c >= CD) return;
  const float bias = bp[c];
  const float* wrow = wl + c*53;
  float acc[8];
#pragma unroll
  for (int r=0;r<8;r++) acc[r]=bias;
#pragma unroll 1
  for (int i0=0; i0<CD; i0+=4) {
    float w0=wrow[i0], w1=wrow[i0+1], w2=wrow[i0+2], w3=wrow[i0+3];
#pragma unroll
    for (int r=0;r<8;r++) {
      float4 a4 = *reinterpret_cast<const float4*>(&al[(rg*8+r)*CD + i0]);
      acc[r] += a4.x*w0 + a4.y*w1 + a4.z*w2 + a4.w*w3;
    }
  }
#pragma unroll
  for (int r=0;r<8;r++) out[(size_t)(r0+rg*8+r)*CD + c] = acc[r];
}

extern "C" void kernel_launch(void* const* d_in, const int* in_sizes, int n_in,
                              void* d_out, int out_size, void* d_ws, size_t ws_size,
                              hipStream_t stream) {
  (void)in_sizes; (void)n_in; (void)out_size; (void)ws_size;
  const float* x        = (const float*)d_in[0];
  const float* w_ih_l0  = (const float*)d_in[1];
  const float* w_hh_l0  = (const float*)d_in[2];
  const float* b_ih_l0  = (const float*)d_in[3];
  const float* b_hh_l0  = (const float*)d_in[4];
  const float* w_ih_l0r = (const float*)d_in[5];
  const float* w_hh_l0r = (const float*)d_in[6];
  const float* b_ih_l0r = (const float*)d_in[7];
  const float* b_hh_l0r = (const float*)d_in[8];
  const float* w_ih_l1  = (const float*)d_in[9];
  const float* w_hh_l1  = (const float*)d_in[10];
  const float* b_ih_l1  = (const float*)d_in[11];
  const float* b_hh_l1  = (const float*)d_in[12];
  const float* w_ih_l1r = (const float*)d_in[13];
  const float* w_hh_l1r = (const float*)d_in[14];
  const float* b_ih_l1r = (const float*)d_in[15];
  const float* b_hh_l1r = (const float*)d_in[16];
  const float* w_qkv    = (const float*)d_in[17];
  const float* b_qkv    = (const float*)d_in[18];
  const float* rpb      = (const float*)d_in[19];
  const float* w_proj   = (const float*)d_in[20];
  const float* b_proj   = (const float*)d_in[21];
  float* out = (float*)d_out;

  float* ws = (float*)d_ws;
  const size_t NPIX = (size_t)TD*PD;          // 11264
  float* XG = ws;
  float* H0 = XG + (size_t)2*PD*TD*GD;
  float* Y  = H0 + NPIX*CD;
  float* Qb = Y  + NPIX*CD;
  unsigned short* Kb = (unsigned short*)(Qb + NPIX*CD);   // [pix][4][16] bf16
  unsigned short* Vb = Kb + NPIX*64;
  float* AO = (float*)(Vb + NPIX*64);

  xg0_kernel<<<dim3(176,2),192,0,stream>>>(x, w_ih_l0, w_ih_l0r, b_ih_l0, b_hh_l0, b_ih_l0r, b_hh_l0r, XG);
  lstm_kernel<<<2*PD,64,0,stream>>>(XG, w_hh_l0, w_hh_l0r, H0, 0);
  xg1_kernel<<<352,192,0,stream>>>(H0, w_ih_l1, w_ih_l1r, b_ih_l1, b_hh_l1, b_ih_l1r, b_hh_l1r, XG);
  lstm_kernel<<<2*PD,64,0,stream>>>(XG, w_hh_l1, w_hh_l1r, Y, 1);

  for (int l=0; l<2; ++l) {
    qkv_kernel<<<352,192,0,stream>>>(Y, w_qkv, b_qkv, Qb, Kb, Vb);
    natten_kernel<<<176,512,0,stream>>>(Qb, Kb, Vb, rpb, AO);
    proj_kernel<<<352,256,0,stream>>>(AO, w_proj, b_proj, (l==1)? out : Y);
  }
}